// Round 10
// baseline (115.479 us; speedup 1.0000x reference)
//
#include <hip/hip_runtime.h>
#include <stdint.h>

// Bahdanau attention: B=64, T=2048, D=256, U=256, all fp32 in/out.
// out = [context (B*D) | attn (B*T)] flat fp32.
#define Bq 64
#define Tq 2048
#define Dq 256
#define Uq 256
#define BT (Bq * Tq)

typedef __bf16 bf16x8 __attribute__((ext_vector_type(8)));
typedef float f32x4 __attribute__((ext_vector_type(4)));

// B LDS: [koct 0..31][u 0..63][16B], stride 1056 (66 dwords -> bank-rotating)
#define BOST 1056
// A LDS: per-wave region [oct 0..3][row 0..63][16B], oct stride 1056
#define AOST 1056
#define AWREG (4 * AOST)   // 4224 per wave

// split fp32 into truncated-bf16 hi + bf16(lo) residual (for w1; quasi-exact)
__device__ inline void split2(float a, unsigned short& h, unsigned short& l) {
  unsigned bits = __float_as_uint(a);
  h = (unsigned short)(bits >> 16);
  float hf = __uint_as_float(bits & 0xffff0000u);
  l = (unsigned short)(__float_as_uint(a - hf) >> 16);
}

// fp32 -> bf16 round-to-nearest-even (features; rel err <= 2^-9)
__device__ inline unsigned short rne_bf16(float a) {
  unsigned b = __float_as_uint(a);
  return (unsigned short)((b + 0x7FFFu + ((b >> 16) & 1u)) >> 16);
}

// tanh(x) = 1 - 2/(exp(2x)+1). ~6 VALU ops, saturates correctly.
__device__ inline float fast_tanh(float x) {
  float e = __expf(2.0f * x);
  return 1.0f - 2.0f * __builtin_amdgcn_rcpf(e + 1.0f);
}

// K0: split w1 [U][D] fp32 -> bf16 hi/lo planes, stored OCTET-MAJOR:
// plane[(k>>3)*U*8 + u*8 + (k&7)]
__global__ void k0_split(const float* __restrict__ w1,
                         unsigned short* __restrict__ hi,
                         unsigned short* __restrict__ lo) {
  int idx = blockIdx.x * 256 + threadIdx.x;
  int i = idx * 4;
  int u = i >> 8;
  int k = i & 255;
  float4 v = *reinterpret_cast<const float4*>(&w1[i]);
  ushort4 h, l;
  split2(v.x, h.x, l.x);
  split2(v.y, h.y, l.y);
  split2(v.z, h.z, l.z);
  split2(v.w, h.w, l.w);
  int dst = (k >> 3) * (Uq * 8) + u * 8 + (k & 7);
  *reinterpret_cast<ushort4*>(&hi[dst]) = h;
  *reinterpret_cast<ushort4*>(&lo[dst]) = l;
}

// K1: comb[b][u] = dot(hidden[b], w2_w[u]) + w2_b[u] + w1_b[u]
__global__ void k1_comb(const float* __restrict__ hidden,
                        const float* __restrict__ w2_w,
                        const float* __restrict__ w2_b,
                        const float* __restrict__ w1_b,
                        float* __restrict__ comb) {
  int b = blockIdx.x;
  int wave = threadIdx.x >> 6;
  int lane = threadIdx.x & 63;
  int u = blockIdx.y * 4 + wave;
  const float* h = hidden + b * Dq;
  const float* w = w2_w + u * Dq;
  float sum = 0.f;
#pragma unroll
  for (int i = 0; i < Dq; i += 64) sum += h[lane + i] * w[lane + i];
#pragma unroll
  for (int m = 32; m >= 1; m >>= 1) sum += __shfl_xor(sum, m, 64);
  if (lane == 0) comb[b * Uq + u] = sum + w2_b[u] + w1_b[u];
}

// K2: partial score over a 64-u slice. BARRIER-FREE main loop.
// Block 256 thr = 4 waves stacked in t: block 256t x 64u per iteration,
// NIT=2 iterations (512-row strip). Wave tile 64t x 64u.
// - B-hi (64u x 256k) DMA'd to LDS once; read-only after single barrier.
// - B-lo fragments from L2-resident global, consumed after 16 hi-MFMAs.
// - A staged wave-privately: lane splits its own rows (RNE bf16), same-wave
//   LDS ordering guarantees correctness with a single buffer. No barriers.
// XCD swizzle: 4 u-slices of one strip land on one XCD -> A re-reads hit L2.
__global__ __launch_bounds__(256) void k2_score(
    const float* __restrict__ feat, const unsigned short* __restrict__ w1hi,
    const unsigned short* __restrict__ w1lo, const float* __restrict__ comb,
    const float* __restrict__ v_w, float* __restrict__ spart) {
  __shared__ char sB[32 * BOST];   // 33792
  __shared__ char sA[4 * AWREG];   // 16896
  const int tid = threadIdx.x;
  const int w = tid >> 6;
  const int l = tid & 63;
  const int fr = l & 15;
  const int g = l >> 4;

  // XCD-aware decode: 4 u-slices of a strip share an XCD, adjacent in dispatch
  const int xcd = blockIdx.x & 7;
  const int idx = blockIdx.x >> 3;     // 0..127
  const int uq = idx & 3;
  const int strip = xcd + 8 * (idx >> 2);   // 0..255
  const int u0 = uq * 64;
  const int r0 = strip * 512;               // flat (b,t) row base
  const int b = strip >> 2;                 // 512 rows per strip, 2048/batch

  // ---- stage B-hi (full K) once: 32 x 1KB DMA, wave w issues 8 ----
#pragma unroll
  for (int q = 0; q < 8; ++q) {
    int j = w * 8 + q;  // k-octet 0..31
    const unsigned short* src = w1hi + (size_t)j * (Uq * 8) + (u0 + l) * 8;
    __builtin_amdgcn_global_load_lds(
        (const __attribute__((address_space(1))) unsigned int*)src,
        (__attribute__((address_space(3))) unsigned int*)(sB + j * BOST), 16,
        0, 0);
  }

  // A staging task: lane handles oct = l&3 of rows (l>>2)+16j, j=0..3
  const int aoct = l & 3;
  const int arb = l >> 2;
  const float* const abase =
      feat + (size_t)(r0 + w * 64) * Dq + aoct * 8;
  char* const awbase = sA + w * AWREG + aoct * AOST;

  float4 pa[8];
  auto loadA = [&](int it, int c) {
#pragma unroll
    for (int j = 0; j < 4; ++j) {
      const float* p = abase + (size_t)(it * 256 + arb + 16 * j) * Dq + c * 32;
      pa[2 * j] = *reinterpret_cast<const float4*>(p);
      pa[2 * j + 1] = *reinterpret_cast<const float4*>(p + 4);
    }
  };
  auto writeA = [&]() {
#pragma unroll
    for (int j = 0; j < 4; ++j) {
      const float4& v0 = pa[2 * j];
      const float4& v1 = pa[2 * j + 1];
      uint4 H;
      H.x = rne_bf16(v0.x) | ((unsigned)rne_bf16(v0.y) << 16);
      H.y = rne_bf16(v0.z) | ((unsigned)rne_bf16(v0.w) << 16);
      H.z = rne_bf16(v1.x) | ((unsigned)rne_bf16(v1.y) << 16);
      H.w = rne_bf16(v1.z) | ((unsigned)rne_bf16(v1.w) << 16);
      *reinterpret_cast<uint4*>(awbase + (arb + 16 * j) * 16) = H;
    }
  };

  // epilogue constants (u indep of iteration)
  float cb[4], vw4[4];
#pragma unroll
  for (int nf = 0; nf < 4; ++nf) {
    int u = u0 + nf * 16 + fr;
    cb[nf] = comb[b * Uq + u];
    vw4[nf] = v_w[u];
  }

  // ---- prologue: stage A(0,0); single barrier also covers B DMA ----
  loadA(0, 0);
  writeA();
  __syncthreads();

  for (int it = 0; it < 2; ++it) {
    f32x4 acc[4][4] = {};
#pragma unroll
    for (int c = 0; c < 8; ++c) {
      const bool lastc = (it == 1) && (c == 7);
      // prefetch next chunk's A into regs (consumed by writeA after MFMA)
      if (!lastc) loadA(c == 7 ? it + 1 : it, c == 7 ? 0 : c + 1);
      // B-lo fragments for current chunk (L2-resident; used by lo-MFMAs)
      bf16x8 blv[4];
#pragma unroll
      for (int nf = 0; nf < 4; ++nf) {
        size_t off =
            (size_t)(c * 4 + g) * (Uq * 8) + (u0 + nf * 16 + fr) * 8;
        blv[nf] = *reinterpret_cast<const bf16x8*>(&w1lo[off]);
      }
      // fragments from LDS
      bf16x8 ah[4], bh[4];
#pragma unroll
      for (int mf = 0; mf < 4; ++mf)
        ah[mf] = *reinterpret_cast<const bf16x8*>(
            sA + w * AWREG + g * AOST + (mf * 16 + fr) * 16);
#pragma unroll
      for (int nf = 0; nf < 4; ++nf)
        bh[nf] = *reinterpret_cast<const bf16x8*>(
            sB + (c * 4 + g) * BOST + (nf * 16 + fr) * 16);
      // hi-plane MFMAs first (LDS-fed), then lo-plane (global-fed)
#pragma unroll
      for (int mf = 0; mf < 4; ++mf)
#pragma unroll
        for (int nf = 0; nf < 4; ++nf)
          acc[mf][nf] = __builtin_amdgcn_mfma_f32_16x16x32_bf16(
              ah[mf], bh[nf], acc[mf][nf], 0, 0, 0);
#pragma unroll
      for (int mf = 0; mf < 4; ++mf)
#pragma unroll
        for (int nf = 0; nf < 4; ++nf)
          acc[mf][nf] = __builtin_amdgcn_mfma_f32_16x16x32_bf16(
              ah[mf], blv[nf], acc[mf][nf], 0, 0, 0);
      // write next chunk's A (after this chunk's ds_reads; in-order per wave)
      if (!lastc) writeA();
    }

    // ---- epilogue (no LDS, no barrier): tanh + v-dot, in-wave u-reduce ----
    // acc[mf][nf][r] is (t_local = mf*16 + g*4 + r, u = u0 + nf*16 + fr)
    float sc[4][4];
#pragma unroll
    for (int mf = 0; mf < 4; ++mf)
#pragma unroll
      for (int r = 0; r < 4; ++r) sc[mf][r] = 0.f;
#pragma unroll
    for (int mf = 0; mf < 4; ++mf)
#pragma unroll
      for (int nf = 0; nf < 4; ++nf)
#pragma unroll
        for (int r = 0; r < 4; ++r)
          sc[mf][r] += vw4[nf] * fast_tanh(acc[mf][nf][r] + cb[nf]);
#pragma unroll
    for (int m = 1; m < 16; m <<= 1)
#pragma unroll
      for (int mf = 0; mf < 4; ++mf)
#pragma unroll
        for (int r = 0; r < 4; ++r)
          sc[mf][r] += __shfl_xor(sc[mf][r], m, 16);
    if (fr == 0) {
      float* dst = spart + (size_t)uq * BT + r0 + it * 256 + w * 64;
#pragma unroll
      for (int mf = 0; mf < 4; ++mf)
        *reinterpret_cast<float4*>(dst + mf * 16 + g * 4) =
            make_float4(sc[mf][0], sc[mf][1], sc[mf][2], sc[mf][3]);
    }
  }
}

// K3: softmax over T per batch; folds the 4 u-slice partials + v_b first.
__global__ void k3_softmax(const float* __restrict__ spart,
                           const float* __restrict__ v_b,
                           float* __restrict__ s) {
  int b = blockIdx.x;
  int tid = threadIdx.x;
  const int base = b * Tq;
  float vb = v_b[0];
  float v[8];
  float m = -1e30f;
#pragma unroll
  for (int i = 0; i < 8; ++i) {
    int idx = base + tid + 256 * i;
    v[i] = spart[idx] + spart[BT + idx] + spart[2 * BT + idx] +
           spart[3 * BT + idx] + vb;
    m = fmaxf(m, v[i]);
  }
#pragma unroll
  for (int mk = 32; mk >= 1; mk >>= 1) m = fmaxf(m, __shfl_xor(m, mk, 64));
  __shared__ float red[4];
  int wv = tid >> 6, ln = tid & 63;
  if (ln == 0) red[wv] = m;
  __syncthreads();
  m = fmaxf(fmaxf(red[0], red[1]), fmaxf(red[2], red[3]));
  __syncthreads();
  float sum = 0.f;
#pragma unroll
  for (int i = 0; i < 8; ++i) {
    v[i] = __expf(v[i] - m);
    sum += v[i];
  }
#pragma unroll
  for (int mk = 32; mk >= 1; mk >>= 1) sum += __shfl_xor(sum, mk, 64);
  if (ln == 0) red[wv] = sum;
  __syncthreads();
  sum = red[0] + red[1] + red[2] + red[3];
  float inv = 1.f / sum;
#pragma unroll
  for (int i = 0; i < 8; ++i) s[base + tid + 256 * i] = v[i] * inv;
}

// K4a: partial context over a 256-t slice
__global__ void k4_partial(const float* __restrict__ feat,
                           const float* __restrict__ attn,
                           float* __restrict__ part) {
  int b = blockIdx.x;
  int ts = blockIdx.y;
  int d = threadIdx.x;
  const int t0 = ts * 256;
  const float* f = feat + ((size_t)(b * Tq + t0)) * Dq + d;
  const float* a = attn + b * Tq + t0;
  float acc = 0.f;
#pragma unroll 8
  for (int t = 0; t < 256; ++t) acc += a[t] * f[(size_t)t * Dq];
  part[(b * 8 + ts) * Dq + d] = acc;
}

// K4b: reduce the 8 partials
__global__ void k4_reduce(const float* __restrict__ part,
                          float* __restrict__ ctx) {
  int b = blockIdx.x;
  int d = threadIdx.x;
  float s = 0.f;
#pragma unroll
  for (int ts = 0; ts < 8; ++ts) s += part[(b * 8 + ts) * Dq + d];
  ctx[b * Dq + d] = s;
}

extern "C" void kernel_launch(void* const* d_in, const int* in_sizes, int n_in,
                              void* d_out, int out_size, void* d_ws,
                              size_t ws_size, hipStream_t stream) {
  const float* feat   = (const float*)d_in[0];
  const float* hidden = (const float*)d_in[1];
  const float* w1_w   = (const float*)d_in[2];
  const float* w1_b   = (const float*)d_in[3];
  const float* w2_w   = (const float*)d_in[4];
  const float* w2_b   = (const float*)d_in[5];
  const float* v_w    = (const float*)d_in[6];
  const float* v_b    = (const float*)d_in[7];

  float* ctx  = (float*)d_out;             // [B][D]
  float* attn = ctx + Bq * Dq;             // [B][T]
  float* comb = (float*)d_ws;              // [B][U]        64 KB
  float* part = comb + Bq * Uq;            // [B][8][D]     512 KB
  float* spart = part + Bq * 8 * Dq;       // [4][B*T]      2 MB
  unsigned short* w1hi = (unsigned short*)(spart + 4 * BT);  // 128 KB
  unsigned short* w1lo = w1hi + Uq * Dq;                      // 128 KB

  k0_split<<<Uq * Dq / 1024, 256, 0, stream>>>(w1_w, w1hi, w1lo);
  k1_comb<<<dim3(Bq, Uq / 4), 256, 0, stream>>>(hidden, w2_w, w2_b, w1_b, comb);
  k2_score<<<1024, 256, 0, stream>>>(feat, w1hi, w1lo, comb, v_w, spart);
  k3_softmax<<<Bq, 256, 0, stream>>>(spart, v_b, attn);
  k4_partial<<<dim3(Bq, 8), 256, 0, stream>>>(feat, attn, part);
  k4_reduce<<<Bq, 256, 0, stream>>>(part, ctx);
}

// Round 11
// 83.043 us; speedup vs baseline: 1.3906x; 1.3906x over previous
//
#include <hip/hip_runtime.h>
#include <stdint.h>

// Bahdanau attention: B=64, T=2048, D=256, U=256, all fp32 in/out.
// out = [context (B*D) | attn (B*T)] flat fp32.
#define Bq 64
#define Tq 2048
#define Dq 256
#define Uq 256

typedef __bf16 bf16x8 __attribute__((ext_vector_type(8)));
typedef float f32x4 __attribute__((ext_vector_type(4)));

// A LDS (bf16 RNE, double-buffered): [oct 0..3][row 0..63][16B]
#define ASTR 1040              // 64*16 + 16 pad
#define ABUF (4 * ASTR)        // 4160 per buffer
// B LDS (bf16 RNE, double-buffered): [oct 0..3][u 0..255][16B]
#define BSTR 4128              // 256*16 + 32 pad
#define BBUF (4 * BSTR)        // 16512 per buffer

// fp32 -> bf16 round-to-nearest-even (rel err <= 2^-9)
__device__ inline unsigned short rne_bf16(float a) {
  unsigned b = __float_as_uint(a);
  return (unsigned short)((b + 0x7FFFu + ((b >> 16) & 1u)) >> 16);
}

// tanh(x) = 1 - 2/(exp(2x)+1). ~6 VALU ops, saturates correctly.
__device__ inline float fast_tanh(float x) {
  float e = __expf(2.0f * x);
  return 1.0f - 2.0f * __builtin_amdgcn_rcpf(e + 1.0f);
}

// K0: w1 [U][D] fp32 -> bf16 RNE, stored OCTET-MAJOR:
// w1bf[(k>>3)*U*8 + u*8 + (k&7)]
__global__ void k0_conv(const float* __restrict__ w1,
                        unsigned short* __restrict__ w1bf) {
  int idx = blockIdx.x * 256 + threadIdx.x;
  int i = idx * 4;
  int u = i >> 8;
  int k = i & 255;
  float4 v = *reinterpret_cast<const float4*>(&w1[i]);
  ushort4 h;
  h.x = rne_bf16(v.x);
  h.y = rne_bf16(v.y);
  h.z = rne_bf16(v.z);
  h.w = rne_bf16(v.w);
  int dst = (k >> 3) * (Uq * 8) + u * 8 + (k & 7);
  *reinterpret_cast<ushort4*>(&w1bf[dst]) = h;
}

// K1: comb[b][u] = dot(hidden[b], w2_w[u]) + w2_b[u] + w1_b[u]  (fp32 exact)
__global__ void k1_comb(const float* __restrict__ hidden,
                        const float* __restrict__ w2_w,
                        const float* __restrict__ w2_b,
                        const float* __restrict__ w1_b,
                        float* __restrict__ comb) {
  int b = blockIdx.x;
  int wave = threadIdx.x >> 6;
  int lane = threadIdx.x & 63;
  int u = blockIdx.y * 4 + wave;
  const float* h = hidden + b * Dq;
  const float* w = w2_w + u * Dq;
  float sum = 0.f;
#pragma unroll
  for (int i = 0; i < Dq; i += 64) sum += h[lane + i] * w[lane + i];
#pragma unroll
  for (int m = 32; m >= 1; m >>= 1) sum += __shfl_xor(sum, m, 64);
  if (lane == 0) comb[b * Uq + u] = sum + w2_b[u] + w1_b[u];
}

// K2: score[b][t] = v_b + sum_u v_w[u] * tanh( feat[b,t,:]·w1_w[u,:] + comb[b][u] )
// Single-plane bf16 MFMA (A=RNE, B=RNE). 256 thr = 4 waves; tile 64t x 256u;
// wave w owns u in [w*64, w*64+64): 4m x 4n fragments of 16x16.
// r9 pipeline, A prefetch deepened to 2 chunks:
//   chunk c: issue B DMA(c+1); loadA(c+2)->regs; ds_read frags(c);
//            setprio(1) 16 MFMA setprio(0); writeA(c+1); barrier.
__global__ __launch_bounds__(256) void k2_score(
    const float* __restrict__ feat, const unsigned short* __restrict__ w1bf,
    const float* __restrict__ comb, const float* __restrict__ v_w,
    const float* __restrict__ v_b, float* __restrict__ score) {
  __shared__ char sB[2 * BBUF];
  __shared__ char sA[2 * ABUF];
  __shared__ float scp[4 * 64];
  const int b = blockIdx.y;
  const int t0 = blockIdx.x * 64;
  const int tid = threadIdx.x;
  const int w = tid >> 6;
  const int l = tid & 63;
  const int fr = l & 15;
  const int g = l >> 4;

  // A staging role: row = tid>>2 (0..63), oct = tid&3; 8 floats per chunk.
  const int arow = tid >> 2;
  const int aoct = tid & 3;
  const float* aload = feat + ((size_t)(b * Tq + t0 + arow)) * Dq + aoct * 8;
  char* const awr = sA + aoct * ASTR + arow * 16;

  f32x4 acc[4][4] = {};
  float4 pa[2][2];

  auto issueBdma = [&](int c) {
    char* bbase = sB + (c & 1) * BBUF;
#pragma unroll
    for (int q = 0; q < 4; ++q) {
      int d = w * 4 + q;         // 0..15
      int j = d >> 2;            // k-octet in chunk
      int h2 = d & 3;            // u-quarter
      const unsigned short* src =
          w1bf + (size_t)(c * 4 + j) * (Uq * 8) + (h2 * 64 + l) * 8;
      __builtin_amdgcn_global_load_lds(
          (const __attribute__((address_space(1))) unsigned int*)src,
          (__attribute__((address_space(3))) unsigned int*)(bbase + j * BSTR +
                                                            h2 * 1024),
          16, 0, 0);
    }
  };
  auto loadA = [&](int c) {
    pa[c & 1][0] = *reinterpret_cast<const float4*>(aload + c * 32);
    pa[c & 1][1] = *reinterpret_cast<const float4*>(aload + c * 32 + 4);
  };
  auto writeA = [&](int c) {
    const float4& v0 = pa[c & 1][0];
    const float4& v1 = pa[c & 1][1];
    uint4 H;
    H.x = rne_bf16(v0.x) | ((unsigned)rne_bf16(v0.y) << 16);
    H.y = rne_bf16(v0.z) | ((unsigned)rne_bf16(v0.w) << 16);
    H.z = rne_bf16(v1.x) | ((unsigned)rne_bf16(v1.y) << 16);
    H.w = rne_bf16(v1.z) | ((unsigned)rne_bf16(v1.w) << 16);
    *reinterpret_cast<uint4*>(awr + (c & 1) * ABUF) = H;
  };

  // ---- prologue: stage chunk 0, prefetch A(1) ----
  issueBdma(0);
  loadA(0);
  loadA(1);
  writeA(0);
  __syncthreads();

  // ---- main loop: one barrier per chunk ----
#pragma unroll
  for (int c = 0; c < 8; ++c) {
    if (c < 7) issueBdma(c + 1);
    if (c < 6) loadA(c + 2);
    const char* bA = sA + (c & 1) * ABUF;
    const char* bB = sB + (c & 1) * BBUF;
    bf16x8 ah[4], bh[4];
#pragma unroll
    for (int mf = 0; mf < 4; ++mf)
      ah[mf] = *reinterpret_cast<const bf16x8*>(bA + g * ASTR +
                                                (mf * 16 + fr) * 16);
#pragma unroll
    for (int nf = 0; nf < 4; ++nf)
      bh[nf] = *reinterpret_cast<const bf16x8*>(
          bB + g * BSTR + (w * 64 + nf * 16 + fr) * 16);
    __builtin_amdgcn_s_setprio(1);
#pragma unroll
    for (int mf = 0; mf < 4; ++mf)
#pragma unroll
      for (int nf = 0; nf < 4; ++nf)
        acc[mf][nf] = __builtin_amdgcn_mfma_f32_16x16x32_bf16(
            ah[mf], bh[nf], acc[mf][nf], 0, 0, 0);
    __builtin_amdgcn_s_setprio(0);
    if (c < 7) {
      writeA(c + 1);
      __syncthreads();
    }
  }

  // ---- epilogue: tanh + v-dot. acc[mf][nf][r] is
  // (t_local = mf*16 + g*4 + r, u = w*64 + nf*16 + fr) ----
  float cb[4], vw4[4];
#pragma unroll
  for (int nf = 0; nf < 4; ++nf) {
    int u = w * 64 + nf * 16 + fr;
    cb[nf] = comb[b * Uq + u];
    vw4[nf] = v_w[u];
  }
  float sc[4][4];
#pragma unroll
  for (int mf = 0; mf < 4; ++mf)
#pragma unroll
    for (int r = 0; r < 4; ++r) sc[mf][r] = 0.f;
#pragma unroll
  for (int mf = 0; mf < 4; ++mf)
#pragma unroll
    for (int nf = 0; nf < 4; ++nf)
#pragma unroll
      for (int r = 0; r < 4; ++r)
        sc[mf][r] += vw4[nf] * fast_tanh(acc[mf][nf][r] + cb[nf]);
#pragma unroll
  for (int m = 1; m < 16; m <<= 1)
#pragma unroll
    for (int mf = 0; mf < 4; ++mf)
#pragma unroll
      for (int r = 0; r < 4; ++r) sc[mf][r] += __shfl_xor(sc[mf][r], m, 16);
  __syncthreads();
  if (fr == 0) {
#pragma unroll
    for (int mf = 0; mf < 4; ++mf)
#pragma unroll
      for (int r = 0; r < 4; ++r)
        scp[w * 64 + mf * 16 + g * 4 + r] = sc[mf][r];
  }
  __syncthreads();
  if (tid < 64) {
    float v = scp[tid] + scp[64 + tid] + scp[128 + tid] + scp[192 + tid];
    score[b * Tq + t0 + tid] = v + v_b[0];
  }
}

// K3: softmax over T per batch, in place. 256 threads, 8 values each.
__global__ void k3_softmax(float* __restrict__ s) {
  int b = blockIdx.x;
  int tid = threadIdx.x;
  const int base = b * Tq;
  float v[8];
  float m = -1e30f;
#pragma unroll
  for (int i = 0; i < 8; ++i) {
    v[i] = s[base + tid + 256 * i];
    m = fmaxf(m, v[i]);
  }
#pragma unroll
  for (int mk = 32; mk >= 1; mk >>= 1) m = fmaxf(m, __shfl_xor(m, mk, 64));
  __shared__ float red[4];
  int wv = tid >> 6, ln = tid & 63;
  if (ln == 0) red[wv] = m;
  __syncthreads();
  m = fmaxf(fmaxf(red[0], red[1]), fmaxf(red[2], red[3]));
  __syncthreads();
  float sum = 0.f;
#pragma unroll
  for (int i = 0; i < 8; ++i) {
    v[i] = __expf(v[i] - m);
    sum += v[i];
  }
#pragma unroll
  for (int mk = 32; mk >= 1; mk >>= 1) sum += __shfl_xor(sum, mk, 64);
  if (ln == 0) red[wv] = sum;
  __syncthreads();
  sum = red[0] + red[1] + red[2] + red[3];
  float inv = 1.f / sum;
#pragma unroll
  for (int i = 0; i < 8; ++i) s[base + tid + 256 * i] = v[i] * inv;
}

// K4a: partial context over a 256-t slice
__global__ void k4_partial(const float* __restrict__ feat,
                           const float* __restrict__ attn,
                           float* __restrict__ part) {
  int b = blockIdx.x;
  int ts = blockIdx.y;
  int d = threadIdx.x;
  const int t0 = ts * 256;
  const float* f = feat + ((size_t)(b * Tq + t0)) * Dq + d;
  const float* a = attn + b * Tq + t0;
  float acc = 0.f;
#pragma unroll 8
  for (int t = 0; t < 256; ++t) acc += a[t] * f[(size_t)t * Dq];
  part[(b * 8 + ts) * Dq + d] = acc;
}

// K4b: reduce the 8 partials
__global__ void k4_reduce(const float* __restrict__ part,
                          float* __restrict__ ctx) {
  int b = blockIdx.x;
  int d = threadIdx.x;
  float s = 0.f;
#pragma unroll
  for (int ts = 0; ts < 8; ++ts) s += part[(b * 8 + ts) * Dq + d];
  ctx[b * Dq + d] = s;
}

extern "C" void kernel_launch(void* const* d_in, const int* in_sizes, int n_in,
                              void* d_out, int out_size, void* d_ws,
                              size_t ws_size, hipStream_t stream) {
  const float* feat   = (const float*)d_in[0];
  const float* hidden = (const float*)d_in[1];
  const float* w1_w   = (const float*)d_in[2];
  const float* w1_b   = (const float*)d_in[3];
  const float* w2_w   = (const float*)d_in[4];
  const float* w2_b   = (const float*)d_in[5];
  const float* v_w    = (const float*)d_in[6];
  const float* v_b    = (const float*)d_in[7];

  float* ctx  = (float*)d_out;             // [B][D]
  float* attn = ctx + Bq * Dq;             // [B][T] (score -> softmax in place)
  float* comb = (float*)d_ws;              // [B][U]        64 KB
  float* part = comb + Bq * Uq;            // [B][8][D]     512 KB
  unsigned short* w1bf = (unsigned short*)(part + Bq * 8 * Dq);  // 128 KB

  k0_conv<<<Uq * Dq / 1024, 256, 0, stream>>>(w1_w, w1bf);
  k1_comb<<<dim3(Bq, Uq / 4), 256, 0, stream>>>(hidden, w2_w, w2_b, w1_b, comb);
  k2_score<<<dim3(Tq / 64, Bq), 256, 0, stream>>>(feat, w1bf, comb, v_w, v_b,
                                                  attn);
  k3_softmax<<<Bq, 256, 0, stream>>>(attn);
  k4_partial<<<dim3(Bq, 8), 256, 0, stream>>>(feat, attn, part);
  k4_reduce<<<Bq, 256, 0, stream>>>(part, ctx);
}

// Round 12
// 73.809 us; speedup vs baseline: 1.5646x; 1.1251x over previous
//
#include <hip/hip_runtime.h>
#include <stdint.h>

// Bahdanau attention: B=64, T=2048, D=256, U=256, all fp32 in/out.
// out = [context (B*D) | attn (B*T)] flat fp32.
#define Bq 64
#define Tq 2048
#define Dq 256
#define Uq 256

typedef __bf16 bf16x8 __attribute__((ext_vector_type(8)));
typedef float f32x4 __attribute__((ext_vector_type(4)));

// A LDS (bf16 RNE, double-buffered): [oct 0..3][row 0..63][16B]
#define ASTR 1040              // 64*16 + 16 pad
#define ABUF (4 * ASTR)        // 4160 per buffer
// B LDS (bf16 RNE, double-buffered): [oct 0..3][u 0..255][16B]
#define BSTR 4128              // 256*16 + 32 pad
#define BBUF (4 * BSTR)        // 16512 per buffer

// fp32 -> bf16 round-to-nearest-even (rel err <= 2^-9)
__device__ inline unsigned short rne_bf16(float a) {
  unsigned b = __float_as_uint(a);
  return (unsigned short)((b + 0x7FFFu + ((b >> 16) & 1u)) >> 16);
}

// tanh(x) = 1 - 2/(exp(2x)+1). ~6 VALU ops, saturates correctly.
__device__ inline float fast_tanh(float x) {
  float e = __expf(2.0f * x);
  return 1.0f - 2.0f * __builtin_amdgcn_rcpf(e + 1.0f);
}

// K01 fused:
//  blocks [0,64):   w1 [U][D] fp32 -> bf16 RNE octet-major w1bf
//  blocks [64,4160): comb[b][u] = dot(hidden[b], w2_w[u]) + w2_b[u] + w1_b[u]
__global__ void k01_prep(const float* __restrict__ w1,
                         unsigned short* __restrict__ w1bf,
                         const float* __restrict__ hidden,
                         const float* __restrict__ w2_w,
                         const float* __restrict__ w2_b,
                         const float* __restrict__ w1_b,
                         float* __restrict__ comb) {
  if (blockIdx.x < 64) {
    int idx = blockIdx.x * 256 + threadIdx.x;
    int i = idx * 4;
    int u = i >> 8;
    int k = i & 255;
    float4 v = *reinterpret_cast<const float4*>(&w1[i]);
    ushort4 h;
    h.x = rne_bf16(v.x);
    h.y = rne_bf16(v.y);
    h.z = rne_bf16(v.z);
    h.w = rne_bf16(v.w);
    int dst = (k >> 3) * (Uq * 8) + u * 8 + (k & 7);
    *reinterpret_cast<ushort4*>(&w1bf[dst]) = h;
  } else {
    int bid = blockIdx.x - 64;
    int b = bid >> 6;
    int wave = threadIdx.x >> 6;
    int lane = threadIdx.x & 63;
    int u = (bid & 63) * 4 + wave;
    const float* h = hidden + b * Dq;
    const float* w = w2_w + u * Dq;
    float sum = 0.f;
#pragma unroll
    for (int i = 0; i < Dq; i += 64) sum += h[lane + i] * w[lane + i];
#pragma unroll
    for (int m = 32; m >= 1; m >>= 1) sum += __shfl_xor(sum, m, 64);
    if (lane == 0) comb[b * Uq + u] = sum + w2_b[u] + w1_b[u];
  }
}

// K2: score[b][t] = v_b + sum_u v_w[u] * tanh( feat[b,t,:]·w1_w[u,:] + comb[b][u] )
// Single-plane bf16 MFMA. 256 thr = 4 waves; tile 64t x 256u; wave 64x64.
// T4 counted-vmcnt barrier: per chunk issue order is pinned to
// [DMA(c+1) x4] -> [A(c+2) x2]; barrier waits vmcnt(2) lgkmcnt(0) so the
// A-prefetch loads stay in flight ACROSS the barrier.
__global__ __launch_bounds__(256) void k2_score(
    const float* __restrict__ feat, const unsigned short* __restrict__ w1bf,
    const float* __restrict__ comb, const float* __restrict__ v_w,
    const float* __restrict__ v_b, float* __restrict__ score) {
  __shared__ char sB[2 * BBUF];
  __shared__ char sA[2 * ABUF];
  __shared__ float scp[4 * 64];
  const int b = blockIdx.y;
  const int t0 = blockIdx.x * 64;
  const int tid = threadIdx.x;
  const int w = tid >> 6;
  const int l = tid & 63;
  const int fr = l & 15;
  const int g = l >> 4;

  // A staging role: row = tid>>2 (0..63), oct = tid&3; 8 floats per chunk.
  const int arow = tid >> 2;
  const int aoct = tid & 3;
  const float* aload = feat + ((size_t)(b * Tq + t0 + arow)) * Dq + aoct * 8;
  char* const awr = sA + aoct * ASTR + arow * 16;

  f32x4 acc[4][4] = {};
  float4 pa[2][2];

  auto issueBdma = [&](int c) {
    char* bbase = sB + (c & 1) * BBUF;
#pragma unroll
    for (int q = 0; q < 4; ++q) {
      int d = w * 4 + q;         // 0..15
      int j = d >> 2;            // k-octet in chunk
      int h2 = d & 3;            // u-quarter
      const unsigned short* src =
          w1bf + (size_t)(c * 4 + j) * (Uq * 8) + (h2 * 64 + l) * 8;
      __builtin_amdgcn_global_load_lds(
          (const __attribute__((address_space(1))) unsigned int*)src,
          (__attribute__((address_space(3))) unsigned int*)(bbase + j * BSTR +
                                                            h2 * 1024),
          16, 0, 0);
    }
  };
  auto loadA = [&](int c) {
    pa[c & 1][0] = *reinterpret_cast<const float4*>(aload + c * 32);
    pa[c & 1][1] = *reinterpret_cast<const float4*>(aload + c * 32 + 4);
  };
  auto writeA = [&](int c) {
    const float4& v0 = pa[c & 1][0];
    const float4& v1 = pa[c & 1][1];
    uint4 H;
    H.x = rne_bf16(v0.x) | ((unsigned)rne_bf16(v0.y) << 16);
    H.y = rne_bf16(v0.z) | ((unsigned)rne_bf16(v0.w) << 16);
    H.z = rne_bf16(v1.x) | ((unsigned)rne_bf16(v1.y) << 16);
    H.w = rne_bf16(v1.z) | ((unsigned)rne_bf16(v1.w) << 16);
    *reinterpret_cast<uint4*>(awr + (c & 1) * ABUF) = H;
  };
  // counted barrier: B-DMAs (older) must be done; 2 newest (A-prefetch) may fly
  auto pipeBarrier = [&]() {
    __builtin_amdgcn_sched_barrier(0);
    asm volatile("s_waitcnt vmcnt(2) lgkmcnt(0)" ::: "memory");
    __builtin_amdgcn_s_barrier();
    __builtin_amdgcn_sched_barrier(0);
  };

  // ---- prologue: order = DMA(0) x4, A(0) x2, A(1) x2; writeA(0) waits A(0)
  issueBdma(0);
  __builtin_amdgcn_sched_barrier(0);
  loadA(0);
  loadA(1);
  __builtin_amdgcn_sched_barrier(0);
  writeA(0);
  pipeBarrier();   // outstanding: A(1) x2 -> vmcnt(2) correct

  // ---- main loop ----
#pragma unroll
  for (int c = 0; c < 8; ++c) {
    if (c < 7) {
      issueBdma(c + 1);                    // 4 vmem (older)
      __builtin_amdgcn_sched_barrier(0);
      loadA((c + 2) & 7);                  // 2 vmem (newer; dummy at c==6)
      __builtin_amdgcn_sched_barrier(0);
    }
    const char* bA = sA + (c & 1) * ABUF;
    const char* bB = sB + (c & 1) * BBUF;
    bf16x8 ah[4], bh[4];
#pragma unroll
    for (int mf = 0; mf < 4; ++mf)
      ah[mf] = *reinterpret_cast<const bf16x8*>(bA + g * ASTR +
                                                (mf * 16 + fr) * 16);
#pragma unroll
    for (int nf = 0; nf < 4; ++nf)
      bh[nf] = *reinterpret_cast<const bf16x8*>(
          bB + g * BSTR + (w * 64 + nf * 16 + fr) * 16);
    __builtin_amdgcn_s_setprio(1);
#pragma unroll
    for (int mf = 0; mf < 4; ++mf)
#pragma unroll
      for (int nf = 0; nf < 4; ++nf)
        acc[mf][nf] = __builtin_amdgcn_mfma_f32_16x16x32_bf16(
            ah[mf], bh[nf], acc[mf][nf], 0, 0, 0);
    __builtin_amdgcn_s_setprio(0);
    if (c < 7) {
      writeA(c + 1);   // compiler waits vmcnt(6) for A(c+1) regs
      pipeBarrier();   // vmcnt(2): DMA(c+1) done, A(c+2) stays in flight
    }
  }

  // ---- epilogue: tanh + v-dot. acc[mf][nf][r] is
  // (t_local = mf*16 + g*4 + r, u = w*64 + nf*16 + fr) ----
  float cb[4], vw4[4];
#pragma unroll
  for (int nf = 0; nf < 4; ++nf) {
    int u = w * 64 + nf * 16 + fr;
    cb[nf] = comb[b * Uq + u];
    vw4[nf] = v_w[u];
  }
  float sc[4][4];
#pragma unroll
  for (int mf = 0; mf < 4; ++mf)
#pragma unroll
    for (int r = 0; r < 4; ++r) sc[mf][r] = 0.f;
#pragma unroll
  for (int mf = 0; mf < 4; ++mf)
#pragma unroll
    for (int nf = 0; nf < 4; ++nf)
#pragma unroll
      for (int r = 0; r < 4; ++r)
        sc[mf][r] += vw4[nf] * fast_tanh(acc[mf][nf][r] + cb[nf]);
#pragma unroll
  for (int m = 1; m < 16; m <<= 1)
#pragma unroll
    for (int mf = 0; mf < 4; ++mf)
#pragma unroll
      for (int r = 0; r < 4; ++r) sc[mf][r] += __shfl_xor(sc[mf][r], m, 16);
  __syncthreads();
  if (fr == 0) {
#pragma unroll
    for (int mf = 0; mf < 4; ++mf)
#pragma unroll
      for (int r = 0; r < 4; ++r)
        scp[w * 64 + mf * 16 + g * 4 + r] = sc[mf][r];
  }
  __syncthreads();
  if (tid < 64) {
    float v = scp[tid] + scp[64 + tid] + scp[128 + tid] + scp[192 + tid];
    score[b * Tq + t0 + tid] = v + v_b[0];
  }
}

// K3: softmax over T per batch, in place; also zeroes ctx row b for K4 atomics.
__global__ void k3_softmax(float* __restrict__ s, float* __restrict__ ctx) {
  int b = blockIdx.x;
  int tid = threadIdx.x;
  const int base = b * Tq;
  ctx[b * Dq + tid] = 0.f;   // Dq == blockDim
  float v[8];
  float m = -1e30f;
#pragma unroll
  for (int i = 0; i < 8; ++i) {
    v[i] = s[base + tid + 256 * i];
    m = fmaxf(m, v[i]);
  }
#pragma unroll
  for (int mk = 32; mk >= 1; mk >>= 1) m = fmaxf(m, __shfl_xor(m, mk, 64));
  __shared__ float red[4];
  int wv = tid >> 6, ln = tid & 63;
  if (ln == 0) red[wv] = m;
  __syncthreads();
  m = fmaxf(fmaxf(red[0], red[1]), fmaxf(red[2], red[3]));
  __syncthreads();
  float sum = 0.f;
#pragma unroll
  for (int i = 0; i < 8; ++i) {
    v[i] = __expf(v[i] - m);
    sum += v[i];
  }
#pragma unroll
  for (int mk = 32; mk >= 1; mk >>= 1) sum += __shfl_xor(sum, mk, 64);
  if (ln == 0) red[wv] = sum;
  __syncthreads();
  sum = red[0] + red[1] + red[2] + red[3];
  float inv = 1.f / sum;
#pragma unroll
  for (int i = 0; i < 8; ++i) s[base + tid + 256 * i] = v[i] * inv;
}

// K4: partial context over a 256-t slice, atomically accumulated into ctx.
__global__ void k4_context(const float* __restrict__ feat,
                           const float* __restrict__ attn,
                           float* __restrict__ ctx) {
  int b = blockIdx.x;
  int ts = blockIdx.y;
  int d = threadIdx.x;
  const int t0 = ts * 256;
  const float* f = feat + ((size_t)(b * Tq + t0)) * Dq + d;
  const float* a = attn + b * Tq + t0;
  float acc = 0.f;
#pragma unroll 8
  for (int t = 0; t < 256; ++t) acc += a[t] * f[(size_t)t * Dq];
  atomicAdd(&ctx[b * Dq + d], acc);
}

extern "C" void kernel_launch(void* const* d_in, const int* in_sizes, int n_in,
                              void* d_out, int out_size, void* d_ws,
                              size_t ws_size, hipStream_t stream) {
  const float* feat   = (const float*)d_in[0];
  const float* hidden = (const float*)d_in[1];
  const float* w1_w   = (const float*)d_in[2];
  const float* w1_b   = (const float*)d_in[3];
  const float* w2_w   = (const float*)d_in[4];
  const float* w2_b   = (const float*)d_in[5];
  const float* v_w    = (const float*)d_in[6];
  const float* v_b    = (const float*)d_in[7];

  float* ctx  = (float*)d_out;             // [B][D]
  float* attn = ctx + Bq * Dq;             // [B][T] (score -> softmax in place)
  float* comb = (float*)d_ws;              // [B][U]        64 KB
  unsigned short* w1bf = (unsigned short*)(comb + Bq * Uq);  // 128 KB

  k01_prep<<<64 + Bq * 64, 256, 0, stream>>>(w1_w, w1bf, hidden, w2_w, w2_b,
                                             w1_b, comb);
  k2_score<<<dim3(Tq / 64, Bq), 256, 0, stream>>>(feat, w1bf, comb, v_w, v_b,
                                                  attn);
  k3_softmax<<<Bq, 256, 0, stream>>>(attn, ctx);
  k4_context<<<dim3(Bq, 8), 256, 0, stream>>>(feat, attn, ctx);
}

// Round 13
// 68.837 us; speedup vs baseline: 1.6776x; 1.0722x over previous
//
#include <hip/hip_runtime.h>
#include <stdint.h>

// Bahdanau attention: B=64, T=2048, D=256, U=256, all fp32 in/out.
// out = [context (B*D) | attn (B*T)] flat fp32.
#define Bq 64
#define Tq 2048
#define Dq 256
#define Uq 256
#define NTILE 32   // T/64 tiles per batch

typedef __bf16 bf16x8 __attribute__((ext_vector_type(8)));
typedef float f32x4 __attribute__((ext_vector_type(4)));

// A LDS (bf16 RNE, double-buffered): [oct 0..3][row 0..63][16B]
#define ASTR 1040              // 64*16 + 16 pad
#define ABUF (4 * ASTR)        // 4160 per buffer
// B LDS (bf16 RNE, double-buffered): [oct 0..3][u 0..255][16B]
#define BSTR 4128              // 256*16 + 32 pad
#define BBUF (4 * BSTR)        // 16512 per buffer

// fp32 -> bf16 round-to-nearest-even (rel err <= 2^-9)
__device__ inline unsigned short rne_bf16(float a) {
  unsigned b = __float_as_uint(a);
  return (unsigned short)((b + 0x7FFFu + ((b >> 16) & 1u)) >> 16);
}

// tanh(x) = 1 - 2/(exp(2x)+1). ~6 VALU ops, saturates correctly.
__device__ inline float fast_tanh(float x) {
  float e = __expf(2.0f * x);
  return 1.0f - 2.0f * __builtin_amdgcn_rcpf(e + 1.0f);
}

// K01 fused:
//  blocks [0,64):   w1 [U][D] fp32 -> bf16 RNE octet-major w1bf
//  blocks [64,4160): comb[b][u] = dot(hidden[b], w2_w[u]) + w2_b[u] + w1_b[u]
__global__ void k01_prep(const float* __restrict__ w1,
                         unsigned short* __restrict__ w1bf,
                         const float* __restrict__ hidden,
                         const float* __restrict__ w2_w,
                         const float* __restrict__ w2_b,
                         const float* __restrict__ w1_b,
                         float* __restrict__ comb) {
  if (blockIdx.x < 64) {
    int idx = blockIdx.x * 256 + threadIdx.x;
    int i = idx * 4;
    int u = i >> 8;
    int k = i & 255;
    float4 v = *reinterpret_cast<const float4*>(&w1[i]);
    ushort4 h;
    h.x = rne_bf16(v.x);
    h.y = rne_bf16(v.y);
    h.z = rne_bf16(v.z);
    h.w = rne_bf16(v.w);
    int dst = (k >> 3) * (Uq * 8) + u * 8 + (k & 7);
    *reinterpret_cast<ushort4*>(&w1bf[dst]) = h;
  } else {
    int bid = blockIdx.x - 64;
    int b = bid >> 6;
    int wave = threadIdx.x >> 6;
    int lane = threadIdx.x & 63;
    int u = (bid & 63) * 4 + wave;
    const float* h = hidden + b * Dq;
    const float* w = w2_w + u * Dq;
    float sum = 0.f;
#pragma unroll
    for (int i = 0; i < Dq; i += 64) sum += h[lane + i] * w[lane + i];
#pragma unroll
    for (int m = 32; m >= 1; m >>= 1) sum += __shfl_xor(sum, m, 64);
    if (lane == 0) comb[b * Uq + u] = sum + w2_b[u] + w1_b[u];
  }
}

// K2: raw score + flash-style partial context for a 64-t tile.
//   score[b][t]     (raw, pre-softmax)
//   pm[b][tile]     = m_blk (max score in tile)
//   partc[b][tile][d] = sum_t exp(score-m_blk) * feat[t][d]   (fp32 feat, L2)
// GEMM core identical to r12 (T4 counted-vmcnt pipeline, single bf16 plane).
__global__ __launch_bounds__(256) void k2_score(
    const float* __restrict__ feat, const unsigned short* __restrict__ w1bf,
    const float* __restrict__ comb, const float* __restrict__ v_w,
    const float* __restrict__ v_b, float* __restrict__ score,
    float* __restrict__ pm, float* __restrict__ partc) {
  __shared__ char sB[2 * BBUF];
  __shared__ char sA[2 * ABUF];
  __shared__ float scp[4 * 64];
  __shared__ float ebuf[64];
  const int b = blockIdx.y;
  const int tile = blockIdx.x;
  const int t0 = tile * 64;
  const int tid = threadIdx.x;
  const int w = tid >> 6;
  const int l = tid & 63;
  const int fr = l & 15;
  const int g = l >> 4;

  // A staging role: row = tid>>2 (0..63), oct = tid&3; 8 floats per chunk.
  const int arow = tid >> 2;
  const int aoct = tid & 3;
  const float* aload = feat + ((size_t)(b * Tq + t0 + arow)) * Dq + aoct * 8;
  char* const awr = sA + aoct * ASTR + arow * 16;

  f32x4 acc[4][4] = {};
  float4 pa[2][2];

  auto issueBdma = [&](int c) {
    char* bbase = sB + (c & 1) * BBUF;
#pragma unroll
    for (int q = 0; q < 4; ++q) {
      int d = w * 4 + q;         // 0..15
      int j = d >> 2;            // k-octet in chunk
      int h2 = d & 3;            // u-quarter
      const unsigned short* src =
          w1bf + (size_t)(c * 4 + j) * (Uq * 8) + (h2 * 64 + l) * 8;
      __builtin_amdgcn_global_load_lds(
          (const __attribute__((address_space(1))) unsigned int*)src,
          (__attribute__((address_space(3))) unsigned int*)(bbase + j * BSTR +
                                                            h2 * 1024),
          16, 0, 0);
    }
  };
  auto loadA = [&](int c) {
    pa[c & 1][0] = *reinterpret_cast<const float4*>(aload + c * 32);
    pa[c & 1][1] = *reinterpret_cast<const float4*>(aload + c * 32 + 4);
  };
  auto writeA = [&](int c) {
    const float4& v0 = pa[c & 1][0];
    const float4& v1 = pa[c & 1][1];
    uint4 H;
    H.x = rne_bf16(v0.x) | ((unsigned)rne_bf16(v0.y) << 16);
    H.y = rne_bf16(v0.z) | ((unsigned)rne_bf16(v0.w) << 16);
    H.z = rne_bf16(v1.x) | ((unsigned)rne_bf16(v1.y) << 16);
    H.w = rne_bf16(v1.z) | ((unsigned)rne_bf16(v1.w) << 16);
    *reinterpret_cast<uint4*>(awr + (c & 1) * ABUF) = H;
  };
  auto pipeBarrier = [&]() {
    __builtin_amdgcn_sched_barrier(0);
    asm volatile("s_waitcnt vmcnt(2) lgkmcnt(0)" ::: "memory");
    __builtin_amdgcn_s_barrier();
    __builtin_amdgcn_sched_barrier(0);
  };

  // ---- prologue ----
  issueBdma(0);
  __builtin_amdgcn_sched_barrier(0);
  loadA(0);
  loadA(1);
  __builtin_amdgcn_sched_barrier(0);
  writeA(0);
  pipeBarrier();

  // ---- main loop ----
#pragma unroll
  for (int c = 0; c < 8; ++c) {
    if (c < 7) {
      issueBdma(c + 1);
      __builtin_amdgcn_sched_barrier(0);
      loadA((c + 2) & 7);
      __builtin_amdgcn_sched_barrier(0);
    }
    const char* bA = sA + (c & 1) * ABUF;
    const char* bB = sB + (c & 1) * BBUF;
    bf16x8 ah[4], bh[4];
#pragma unroll
    for (int mf = 0; mf < 4; ++mf)
      ah[mf] = *reinterpret_cast<const bf16x8*>(bA + g * ASTR +
                                                (mf * 16 + fr) * 16);
#pragma unroll
    for (int nf = 0; nf < 4; ++nf)
      bh[nf] = *reinterpret_cast<const bf16x8*>(
          bB + g * BSTR + (w * 64 + nf * 16 + fr) * 16);
    __builtin_amdgcn_s_setprio(1);
#pragma unroll
    for (int mf = 0; mf < 4; ++mf)
#pragma unroll
      for (int nf = 0; nf < 4; ++nf)
        acc[mf][nf] = __builtin_amdgcn_mfma_f32_16x16x32_bf16(
            ah[mf], bh[nf], acc[mf][nf], 0, 0, 0);
    __builtin_amdgcn_s_setprio(0);
    if (c < 7) {
      writeA(c + 1);
      pipeBarrier();
    }
  }

  // ---- epilogue 1: tanh + v-dot -> raw scores ----
  float cb[4], vw4[4];
#pragma unroll
  for (int nf = 0; nf < 4; ++nf) {
    int u = w * 64 + nf * 16 + fr;
    cb[nf] = comb[b * Uq + u];
    vw4[nf] = v_w[u];
  }
  float sc[4][4];
#pragma unroll
  for (int mf = 0; mf < 4; ++mf)
#pragma unroll
    for (int r = 0; r < 4; ++r) sc[mf][r] = 0.f;
#pragma unroll
  for (int mf = 0; mf < 4; ++mf)
#pragma unroll
    for (int nf = 0; nf < 4; ++nf)
#pragma unroll
      for (int r = 0; r < 4; ++r)
        sc[mf][r] += vw4[nf] * fast_tanh(acc[mf][nf][r] + cb[nf]);
#pragma unroll
  for (int m = 1; m < 16; m <<= 1)
#pragma unroll
    for (int mf = 0; mf < 4; ++mf)
#pragma unroll
      for (int r = 0; r < 4; ++r) sc[mf][r] += __shfl_xor(sc[mf][r], m, 16);
  __syncthreads();
  if (fr == 0) {
#pragma unroll
    for (int mf = 0; mf < 4; ++mf)
#pragma unroll
      for (int r = 0; r < 4; ++r)
        scp[w * 64 + mf * 16 + g * 4 + r] = sc[mf][r];
  }
  __syncthreads();
  // ---- epilogue 2: finalize scores, block max, exp weights ----
  if (tid < 64) {
    float v =
        scp[tid] + scp[64 + tid] + scp[128 + tid] + scp[192 + tid] + v_b[0];
    score[b * Tq + t0 + tid] = v;
    float m = v;
#pragma unroll
    for (int mk = 32; mk >= 1; mk >>= 1) m = fmaxf(m, __shfl_xor(m, mk, 64));
    ebuf[tid] = __expf(v - m);
    if (tid == 0) pm[b * NTILE + tile] = m;
  }
  __syncthreads();
  // ---- epilogue 3: partial context (fp32 features, L2-hot tile) ----
  {
    const float* frow = feat + (size_t)(b * Tq + t0) * Dq + tid;
    float cd = 0.f;
#pragma unroll 8
    for (int t = 0; t < 64; ++t) cd += ebuf[t] * frow[(size_t)t * Dq];
    partc[((size_t)b * NTILE + tile) * Dq + tid] = cd;
  }
}

// K3: softmax over T per batch (in place on raw scores); writes M, invS.
__global__ void k3_softmax(float* __restrict__ s, float* __restrict__ stats) {
  int b = blockIdx.x;
  int tid = threadIdx.x;
  const int base = b * Tq;
  float v[8];
  float m = -1e30f;
#pragma unroll
  for (int i = 0; i < 8; ++i) {
    v[i] = s[base + tid + 256 * i];
    m = fmaxf(m, v[i]);
  }
#pragma unroll
  for (int mk = 32; mk >= 1; mk >>= 1) m = fmaxf(m, __shfl_xor(m, mk, 64));
  __shared__ float red[4];
  int wv = tid >> 6, ln = tid & 63;
  if (ln == 0) red[wv] = m;
  __syncthreads();
  m = fmaxf(fmaxf(red[0], red[1]), fmaxf(red[2], red[3]));
  __syncthreads();
  float sum = 0.f;
#pragma unroll
  for (int i = 0; i < 8; ++i) {
    v[i] = __expf(v[i] - m);
    sum += v[i];
  }
#pragma unroll
  for (int mk = 32; mk >= 1; mk >>= 1) sum += __shfl_xor(sum, mk, 64);
  if (ln == 0) red[wv] = sum;
  __syncthreads();
  sum = red[0] + red[1] + red[2] + red[3];
  float inv = 1.f / sum;
#pragma unroll
  for (int i = 0; i < 8; ++i) s[base + tid + 256 * i] = v[i] * inv;
  if (tid == 0) {
    stats[b * 2 + 0] = m;
    stats[b * 2 + 1] = inv;
  }
}

// K5: combine partial contexts: ctx[b][d] = invS * sum_j exp(m_j - M) * partc_j[d]
__global__ void k5_combine(const float* __restrict__ partc,
                           const float* __restrict__ pm,
                           const float* __restrict__ stats,
                           float* __restrict__ ctx) {
  int b = blockIdx.x;
  int d = threadIdx.x;
  const float M = stats[b * 2 + 0];
  const float invS = stats[b * 2 + 1];
  __shared__ float wgt[NTILE];
  if (d < NTILE) wgt[d] = __expf(pm[b * NTILE + d] - M);
  __syncthreads();
  float s = 0.f;
#pragma unroll
  for (int j = 0; j < NTILE; ++j)
    s += wgt[j] * partc[((size_t)b * NTILE + j) * Dq + d];
  ctx[b * Dq + d] = s * invS;
}

extern "C" void kernel_launch(void* const* d_in, const int* in_sizes, int n_in,
                              void* d_out, int out_size, void* d_ws,
                              size_t ws_size, hipStream_t stream) {
  const float* feat   = (const float*)d_in[0];
  const float* hidden = (const float*)d_in[1];
  const float* w1_w   = (const float*)d_in[2];
  const float* w1_b   = (const float*)d_in[3];
  const float* w2_w   = (const float*)d_in[4];
  const float* w2_b   = (const float*)d_in[5];
  const float* v_w    = (const float*)d_in[6];
  const float* v_b    = (const float*)d_in[7];

  float* ctx  = (float*)d_out;             // [B][D]
  float* attn = ctx + Bq * Dq;             // [B][T] (raw score -> softmax)
  float* comb = (float*)d_ws;              // [B][U]            64 KB
  unsigned short* w1bf = (unsigned short*)(comb + Bq * Uq);   // 128 KB
  float* partc = (float*)(w1bf + Uq * Dq); // [B][32][D]        2 MB
  float* pm    = partc + (size_t)Bq * NTILE * Dq;  // [B][32]   8 KB
  float* stats = pm + Bq * NTILE;          // [B][2]

  k01_prep<<<64 + Bq * 64, 256, 0, stream>>>(w1_w, w1bf, hidden, w2_w, w2_b,
                                             w1_b, comb);
  k2_score<<<dim3(NTILE, Bq), 256, 0, stream>>>(feat, w1bf, comb, v_w, v_b,
                                                attn, pm, partc);
  k3_softmax<<<Bq, 256, 0, stream>>>(attn, stats);
  k5_combine<<<Bq, 256, 0, stream>>>(partc, pm, stats, ctx);
}

// Round 14
// 62.096 us; speedup vs baseline: 1.8597x; 1.1086x over previous
//
#include <hip/hip_runtime.h>
#include <stdint.h>

// Bahdanau attention: B=64, T=2048, D=256, U=256, all fp32 in/out.
// out = [context (B*D) | attn (B*T)] flat fp32.
#define Bq 64
#define Tq 2048
#define Dq 256
#define Uq 256
#define NTILE 32   // T/64 tiles per batch

typedef __bf16 bf16x8 __attribute__((ext_vector_type(8)));
typedef float f32x4 __attribute__((ext_vector_type(4)));

// A LDS (bf16 RNE, double-buffered): [oct 0..3][row 0..63][16B]
#define ASTR 1040              // 64*16 + 16 pad
#define ABUF (4 * ASTR)        // 4160 per buffer
// B LDS (bf16 RNE, double-buffered): [oct 0..3][u 0..255][16B]
#define BSTR 4128              // 256*16 + 32 pad
#define BBUF (4 * BSTR)        // 16512 per buffer

// fp32 -> bf16 round-to-nearest-even (rel err <= 2^-9)
__device__ inline unsigned short rne_bf16(float a) {
  unsigned b = __float_as_uint(a);
  return (unsigned short)((b + 0x7FFFu + ((b >> 16) & 1u)) >> 16);
}

// tanh(x) = 1 - 2/(exp(2x)+1). ~6 VALU ops, saturates correctly.
__device__ inline float fast_tanh(float x) {
  float e = __expf(2.0f * x);
  return 1.0f - 2.0f * __builtin_amdgcn_rcpf(e + 1.0f);
}

// K01 fused:
//  blocks [0,64):   w1 [U][D] fp32 -> bf16 RNE octet-major w1bf
//  blocks [64,4160): comb[b][u] = dot(hidden[b], w2_w[u]) + w2_b[u] + w1_b[u]
__global__ void k01_prep(const float* __restrict__ w1,
                         unsigned short* __restrict__ w1bf,
                         const float* __restrict__ hidden,
                         const float* __restrict__ w2_w,
                         const float* __restrict__ w2_b,
                         const float* __restrict__ w1_b,
                         float* __restrict__ comb) {
  if (blockIdx.x < 64) {
    int idx = blockIdx.x * 256 + threadIdx.x;
    int i = idx * 4;
    int u = i >> 8;
    int k = i & 255;
    float4 v = *reinterpret_cast<const float4*>(&w1[i]);
    ushort4 h;
    h.x = rne_bf16(v.x);
    h.y = rne_bf16(v.y);
    h.z = rne_bf16(v.z);
    h.w = rne_bf16(v.w);
    int dst = (k >> 3) * (Uq * 8) + u * 8 + (k & 7);
    *reinterpret_cast<ushort4*>(&w1bf[dst]) = h;
  } else {
    int bid = blockIdx.x - 64;
    int b = bid >> 6;
    int wave = threadIdx.x >> 6;
    int lane = threadIdx.x & 63;
    int u = (bid & 63) * 4 + wave;
    const float* h = hidden + b * Dq;
    const float* w = w2_w + u * Dq;
    float sum = 0.f;
#pragma unroll
    for (int i = 0; i < Dq; i += 64) sum += h[lane + i] * w[lane + i];
#pragma unroll
    for (int m = 32; m >= 1; m >>= 1) sum += __shfl_xor(sum, m, 64);
    if (lane == 0) comb[b * Uq + u] = sum + w2_b[u] + w1_b[u];
  }
}

// K2: raw score + flash-style partial context for a 64-t tile.
// Context feature loads are issued EARLY (before the tanh/reduce phase) so
// their L2/HBM latency hides under epilogue VALU work (T14).
__global__ __launch_bounds__(256) void k2_score(
    const float* __restrict__ feat, const unsigned short* __restrict__ w1bf,
    const float* __restrict__ comb, const float* __restrict__ v_w,
    const float* __restrict__ v_b, float* __restrict__ score,
    float* __restrict__ pm, float* __restrict__ partc) {
  __shared__ char sB[2 * BBUF];
  __shared__ char sA[2 * ABUF];
  __shared__ float scp[4 * 64];
  __shared__ float ebuf[64];
  const int b = blockIdx.y;
  const int tile = blockIdx.x;
  const int t0 = tile * 64;
  const int tid = threadIdx.x;
  const int w = tid >> 6;
  const int l = tid & 63;
  const int fr = l & 15;
  const int g = l >> 4;

  // A staging role: row = tid>>2 (0..63), oct = tid&3; 8 floats per chunk.
  const int arow = tid >> 2;
  const int aoct = tid & 3;
  const float* aload = feat + ((size_t)(b * Tq + t0 + arow)) * Dq + aoct * 8;
  char* const awr = sA + aoct * ASTR + arow * 16;

  f32x4 acc[4][4] = {};
  float4 pa[2][2];

  auto issueBdma = [&](int c) {
    char* bbase = sB + (c & 1) * BBUF;
#pragma unroll
    for (int q = 0; q < 4; ++q) {
      int d = w * 4 + q;         // 0..15
      int j = d >> 2;            // k-octet in chunk
      int h2 = d & 3;            // u-quarter
      const unsigned short* src =
          w1bf + (size_t)(c * 4 + j) * (Uq * 8) + (h2 * 64 + l) * 8;
      __builtin_amdgcn_global_load_lds(
          (const __attribute__((address_space(1))) unsigned int*)src,
          (__attribute__((address_space(3))) unsigned int*)(bbase + j * BSTR +
                                                            h2 * 1024),
          16, 0, 0);
    }
  };
  auto loadA = [&](int c) {
    pa[c & 1][0] = *reinterpret_cast<const float4*>(aload + c * 32);
    pa[c & 1][1] = *reinterpret_cast<const float4*>(aload + c * 32 + 4);
  };
  auto writeA = [&](int c) {
    const float4& v0 = pa[c & 1][0];
    const float4& v1 = pa[c & 1][1];
    uint4 H;
    H.x = rne_bf16(v0.x) | ((unsigned)rne_bf16(v0.y) << 16);
    H.y = rne_bf16(v0.z) | ((unsigned)rne_bf16(v0.w) << 16);
    H.z = rne_bf16(v1.x) | ((unsigned)rne_bf16(v1.y) << 16);
    H.w = rne_bf16(v1.z) | ((unsigned)rne_bf16(v1.w) << 16);
    *reinterpret_cast<uint4*>(awr + (c & 1) * ABUF) = H;
  };
  auto pipeBarrier = [&]() {
    __builtin_amdgcn_sched_barrier(0);
    asm volatile("s_waitcnt vmcnt(2) lgkmcnt(0)" ::: "memory");
    __builtin_amdgcn_s_barrier();
    __builtin_amdgcn_sched_barrier(0);
  };

  // ---- prologue ----
  issueBdma(0);
  __builtin_amdgcn_sched_barrier(0);
  loadA(0);
  loadA(1);
  __builtin_amdgcn_sched_barrier(0);
  writeA(0);
  pipeBarrier();

  // ---- main loop ----
#pragma unroll
  for (int c = 0; c < 8; ++c) {
    if (c < 7) {
      issueBdma(c + 1);
      __builtin_amdgcn_sched_barrier(0);
      loadA((c + 2) & 7);
      __builtin_amdgcn_sched_barrier(0);
    }
    const char* bA = sA + (c & 1) * ABUF;
    const char* bB = sB + (c & 1) * BBUF;
    bf16x8 ah[4], bh[4];
#pragma unroll
    for (int mf = 0; mf < 4; ++mf)
      ah[mf] = *reinterpret_cast<const bf16x8*>(bA + g * ASTR +
                                                (mf * 16 + fr) * 16);
#pragma unroll
    for (int nf = 0; nf < 4; ++nf)
      bh[nf] = *reinterpret_cast<const bf16x8*>(
          bB + g * BSTR + (w * 64 + nf * 16 + fr) * 16);
    __builtin_amdgcn_s_setprio(1);
#pragma unroll
    for (int mf = 0; mf < 4; ++mf)
#pragma unroll
      for (int nf = 0; nf < 4; ++nf)
        acc[mf][nf] = __builtin_amdgcn_mfma_f32_16x16x32_bf16(
            ah[mf], bh[nf], acc[mf][nf], 0, 0, 0);
    __builtin_amdgcn_s_setprio(0);
    if (c < 7) {
      writeA(c + 1);
      pipeBarrier();
    }
  }

  // ---- issue first half of context feature loads EARLY (independent of
  // scores; latency hides under the tanh/reduce phase below) ----
  const float* frow = feat + (size_t)(b * Tq + t0) * Dq + tid;
  float fv0[16], fv1[16];
#pragma unroll
  for (int t = 0; t < 16; ++t) fv0[t] = frow[(size_t)t * Dq];
#pragma unroll
  for (int t = 0; t < 16; ++t) fv1[t] = frow[(size_t)(t + 16) * Dq];

  // ---- epilogue 1: tanh + v-dot -> raw scores ----
  float cb[4], vw4[4];
#pragma unroll
  for (int nf = 0; nf < 4; ++nf) {
    int u = w * 64 + nf * 16 + fr;
    cb[nf] = comb[b * Uq + u];
    vw4[nf] = v_w[u];
  }
  float sc[4][4];
#pragma unroll
  for (int mf = 0; mf < 4; ++mf)
#pragma unroll
    for (int r = 0; r < 4; ++r) sc[mf][r] = 0.f;
#pragma unroll
  for (int mf = 0; mf < 4; ++mf)
#pragma unroll
    for (int nf = 0; nf < 4; ++nf)
#pragma unroll
      for (int r = 0; r < 4; ++r)
        sc[mf][r] += vw4[nf] * fast_tanh(acc[mf][nf][r] + cb[nf]);
#pragma unroll
  for (int m = 1; m < 16; m <<= 1)
#pragma unroll
    for (int mf = 0; mf < 4; ++mf)
#pragma unroll
      for (int r = 0; r < 4; ++r) sc[mf][r] += __shfl_xor(sc[mf][r], m, 16);
  __syncthreads();
  if (fr == 0) {
#pragma unroll
    for (int mf = 0; mf < 4; ++mf)
#pragma unroll
      for (int r = 0; r < 4; ++r)
        scp[w * 64 + mf * 16 + g * 4 + r] = sc[mf][r];
  }
  __syncthreads();
  // ---- epilogue 2: finalize scores, block max, exp weights ----
  if (tid < 64) {
    float v =
        scp[tid] + scp[64 + tid] + scp[128 + tid] + scp[192 + tid] + v_b[0];
    score[b * Tq + t0 + tid] = v;
    float m = v;
#pragma unroll
    for (int mk = 32; mk >= 1; mk >>= 1) m = fmaxf(m, __shfl_xor(m, mk, 64));
    ebuf[tid] = __expf(v - m);
    if (tid == 0) pm[b * NTILE + tile] = m;
  }
  __syncthreads();
  // ---- epilogue 3: partial context; second half issued interleaved ----
  {
    float fv2[16], fv3[16];
#pragma unroll
    for (int t = 0; t < 16; ++t) fv2[t] = frow[(size_t)(t + 32) * Dq];
    float cd = 0.f;
#pragma unroll
    for (int t = 0; t < 16; ++t) cd += ebuf[t] * fv0[t];
#pragma unroll
    for (int t = 0; t < 16; ++t) fv3[t] = frow[(size_t)(t + 48) * Dq];
#pragma unroll
    for (int t = 0; t < 16; ++t) cd += ebuf[t + 16] * fv1[t];
#pragma unroll
    for (int t = 0; t < 16; ++t) cd += ebuf[t + 32] * fv2[t];
#pragma unroll
    for (int t = 0; t < 16; ++t) cd += ebuf[t + 48] * fv3[t];
    partc[((size_t)b * NTILE + tile) * Dq + tid] = cd;
  }
}

// K35 fused: softmax over T per batch (in place) + context combine.
// ctx[b][d] = invS * sum_j exp(m_j - M) * partc[b][j][d]
__global__ void k35_softmax_combine(float* __restrict__ s,
                                    const float* __restrict__ pm,
                                    const float* __restrict__ partc,
                                    float* __restrict__ ctx) {
  int b = blockIdx.x;
  int tid = threadIdx.x;
  const int base = b * Tq;
  float v[8];
  float m = -1e30f;
#pragma unroll
  for (int i = 0; i < 8; ++i) {
    v[i] = s[base + tid + 256 * i];
    m = fmaxf(m, v[i]);
  }
#pragma unroll
  for (int mk = 32; mk >= 1; mk >>= 1) m = fmaxf(m, __shfl_xor(m, mk, 64));
  __shared__ float red[4];
  int wv = tid >> 6, ln = tid & 63;
  if (ln == 0) red[wv] = m;
  __syncthreads();
  m = fmaxf(fmaxf(red[0], red[1]), fmaxf(red[2], red[3]));
  __syncthreads();
  float sum = 0.f;
#pragma unroll
  for (int i = 0; i < 8; ++i) {
    v[i] = __expf(v[i] - m);
    sum += v[i];
  }
#pragma unroll
  for (int mk = 32; mk >= 1; mk >>= 1) sum += __shfl_xor(sum, mk, 64);
  if (ln == 0) red[wv] = sum;
  __syncthreads();
  sum = red[0] + red[1] + red[2] + red[3];
  float inv = 1.f / sum;
#pragma unroll
  for (int i = 0; i < 8; ++i) s[base + tid + 256 * i] = v[i] * inv;

  // combine partial contexts
  __shared__ float wgt[NTILE];
  if (tid < NTILE) wgt[tid] = __expf(pm[b * NTILE + tid] - m);
  __syncthreads();
  float cs = 0.f;
#pragma unroll
  for (int j = 0; j < NTILE; ++j)
    cs += wgt[j] * partc[((size_t)b * NTILE + j) * Dq + tid];
  ctx[b * Dq + tid] = cs * inv;
}

extern "C" void kernel_launch(void* const* d_in, const int* in_sizes, int n_in,
                              void* d_out, int out_size, void* d_ws,
                              size_t ws_size, hipStream_t stream) {
  const float* feat   = (const float*)d_in[0];
  const float* hidden = (const float*)d_in[1];
  const float* w1_w   = (const float*)d_in[2];
  const float* w1_b   = (const float*)d_in[3];
  const float* w2_w   = (const float*)d_in[4];
  const float* w2_b   = (const float*)d_in[5];
  const float* v_w    = (const float*)d_in[6];
  const float* v_b    = (const float*)d_in[7];

  float* ctx  = (float*)d_out;             // [B][D]
  float* attn = ctx + Bq * Dq;             // [B][T] (raw score -> softmax)
  float* comb = (float*)d_ws;              // [B][U]            64 KB
  unsigned short* w1bf = (unsigned short*)(comb + Bq * Uq);   // 128 KB
  float* partc = (float*)(w1bf + Uq * Dq); // [B][32][D]        2 MB
  float* pm    = partc + (size_t)Bq * NTILE * Dq;  // [B][32]   8 KB

  k01_prep<<<64 + Bq * 64, 256, 0, stream>>>(w1_w, w1bf, hidden, w2_w, w2_b,
                                             w1_b, comb);
  k2_score<<<dim3(NTILE, Bq), 256, 0, stream>>>(feat, w1bf, comb, v_w, v_b,
                                                attn, pm, partc);
  k35_softmax_combine<<<Bq, 256, 0, stream>>>(attn, pm, partc, ctx);
}